// Round 24
// baseline (140.209 us; speedup 1.0000x reference)
//
#include <hip/hip_runtime.h>

#define SQ 2048
#define DM 1024
#define NH 16
#define HD 64

typedef __bf16 bf16x8 __attribute__((ext_vector_type(8)));
typedef float f32x4 __attribute__((ext_vector_type(4)));
typedef unsigned short u16;
typedef unsigned int u32;

// fp32 -> bf16 round-to-nearest-even (bulk convert pass)
__device__ __forceinline__ u16 f2b(float f) {
  union { float f; u32 u; } c; c.f = f;
  return (u16)((c.u + 0x7FFFu + ((c.u >> 16) & 1u)) >> 16);
}

// async global->LDS, 16B per lane; lds dest = wave-uniform base + lane*16
__device__ __forceinline__ void gll16(const void* g, void* l) {
  __builtin_amdgcn_global_load_lds(
      (const __attribute__((address_space(1))) void*)g,
      (__attribute__((address_space(3))) void*)l, 16, 0, 0);
}

// ---------------------------------------------------------------------------
// fp32 -> bf16 convert pass: X (4M elems) + Wq/Wk/Wv/Wo (1M each)
// ---------------------------------------------------------------------------
__global__ void __launch_bounds__(256) conv_bf16(
    const float* __restrict__ X,
    const float* __restrict__ Wq, const float* __restrict__ Wk,
    const float* __restrict__ Wv, const float* __restrict__ Wo,
    u16* __restrict__ Xb, u16* __restrict__ Wqb, u16* __restrict__ Wkb,
    u16* __restrict__ Wvb, u16* __restrict__ Wob) {
  const size_t e = ((size_t)blockIdx.x * 256 + threadIdx.x) * 8;
  const float* src; u16* dst; size_t rel;
  if (e < 4194304u)      { src = X;  dst = Xb;  rel = e; }
  else if (e < 5242880u) { src = Wq; dst = Wqb; rel = e - 4194304u; }
  else if (e < 6291456u) { src = Wk; dst = Wkb; rel = e - 5242880u; }
  else if (e < 7340032u) { src = Wv; dst = Wvb; rel = e - 6291456u; }
  else                   { src = Wo; dst = Wob; rel = e - 7340032u; }
  float4 a = *(const float4*)(src + rel);
  float4 b = *(const float4*)(src + rel + 4);
  union { u16 h[8]; uint4 v; } o;
  o.h[0] = f2b(a.x); o.h[1] = f2b(a.y); o.h[2] = f2b(a.z); o.h[3] = f2b(a.w);
  o.h[4] = f2b(b.x); o.h[5] = f2b(b.y); o.h[6] = f2b(b.z); o.h[7] = f2b(b.w);
  *(uint4*)(dst + rel) = o.v;
}

// ---------------------------------------------------------------------------
// mean_v2: per (bh, stripe): compute mean(V), fill masked q-rows of Ao;
// block (0,0) builds the active-tile work list.
// ---------------------------------------------------------------------------
__global__ void __launch_bounds__(256) mean_v2(
    const u16* __restrict__ Vt, const int* __restrict__ vlen,
    u16* __restrict__ Ao, int* __restrict__ wl) {
  __shared__ float part[256];
  __shared__ float smv[64];
  const int bh = blockIdx.x, c8 = blockIdx.y;
  const int t = threadIdx.x, d = t >> 2, c = t & 3;
  const u16* row = Vt + ((size_t)bh * HD + d) * SQ + c * 512;
  float s = 0.f;
  for (int i = 0; i < 64; ++i) {
    bf16x8 v = *(const bf16x8*)(row + i * 8);
    s += ((float)v[0] + (float)v[1]) + ((float)v[2] + (float)v[3])
       + ((float)v[4] + (float)v[5]) + ((float)v[6] + (float)v[7]);
  }
  part[t] = s;
  __syncthreads();
  if (c == 0) {
    const float tot = (part[t] + part[t + 1]) + (part[t + 2] + part[t + 3]);
    smv[d] = tot * (1.0f / 2048.0f);
  }
  __syncthreads();

  const int vl = vlen[bh];
  const int ft = (vl + 63) >> 6;
  const int b = bh >> 4, h = bh & 15;
  const int c16 = t & 15, r16 = t >> 4;
  union { u16 h4[4]; uint2 u; } pv;
#pragma unroll
  for (int j = 0; j < 4; ++j) pv.h4[j] = f2b(smv[c16 * 4 + j]);
  for (int ss = ft * 64 + c8 * 16 + r16; ss < SQ; ss += 128)
    *(uint2*)(Ao + ((size_t)(b * SQ + ss)) * DM + h * HD + c16 * 4) = pv.u;

  if (bh == 0 && c8 == 0) {
    __shared__ int nts[32], off[32];
    if (t < 32) {
      int nt = (vlen[t] + 63) >> 6;
      if (nt > 32) nt = 32;
      nts[t] = nt;
    }
    __syncthreads();
    if (t == 0) {
      int acc = 0;
      for (int i = 0; i < 32; ++i) { off[i] = acc; acc += nts[i]; }
      wl[0] = acc;
    }
    __syncthreads();
    if (t < 32) {
      const int o = off[t], nt = nts[t];
      for (int q = 0; q < nt; ++q) wl[1 + o + q] = (t << 5) | q;
    }
  }
}

// ---------------------------------------------------------------------------
// Merged QKV projection v3: PORT OF THE MEASURED out_gemm STRUCTURE (716 TF):
// 64x128 tile, BK=32, 2-buffer dbuf, plain __syncthreads, ~6 blocks/CU.
// Grid 1536 (24 n x 64 m), XCD-bijective swizzle. Mode-0 (Q) blocks whose
// 64-row s-range is masked for both covered heads are skipped.
// ---------------------------------------------------------------------------
__global__ void __launch_bounds__(256) qkv_gemm64(
    const u16* __restrict__ Xb, const u16* __restrict__ Wqkv,
    const float* __restrict__ bq, const float* __restrict__ bk, const float* __restrict__ bv,
    const int* __restrict__ vlen,
    u16* __restrict__ Qb, u16* __restrict__ Kb, u16* __restrict__ Vt) {
  __shared__ u16 sA[2][2048];   // [64][32] u16 per buf
  __shared__ u16 sB[2][4096];   // [128][32] u16 per buf
  const int t = threadIdx.x, l = t & 63, w = t >> 6;
  const int wr = w >> 1, wc = w & 1, lg = l >> 4, li = l & 15;
  const int id = blockIdx.x;
  const int swz = (id & 7) * 192 + (id >> 3);   // bijective: nwg=1536
  const int bx = swz % 24, by = swz / 24;
  const int m0 = by * 64, n0 = bx * 128;
  const int mode = n0 >> 10;                    // 0:Q 1:K 2:V (block-uniform)
  const float* bias = (mode == 0) ? bq : (mode == 1) ? bk : bv;

  if (mode == 0) {
    // block covers 2 heads, s-range [s0, s0+63]; skip if all rows masked
    const int bb = m0 >> 11, s0 = m0 & 2047, h0 = n0 >> 6;
    if (s0 >= vlen[bb * NH + h0] && s0 >= vlen[bb * NH + h0 + 1]) return;
  }

  auto stage = [&](int buf, int kt) {
    {
      const int s = w * 64 + l;          // A slot 0..255
      const int r = s >> 2, cc = s & 3;
      gll16(Xb + (size_t)(m0 + r) * DM + kt * 32 + cc * 8, &sA[buf][w * 512]);
    }
#pragma unroll
    for (int c = 0; c < 2; ++c) {
      const int g = w * 2 + c;           // B chunk 0..7
      const int s = g * 64 + l;          // B slot 0..511
      const int r = s >> 2, cc = s & 3;
      gll16(Wqkv + (size_t)(n0 + r) * DM + kt * 32 + cc * 8, &sB[buf][g * 512]);
    }
  };

  f32x4 acc[2][4];
  f32x4 z4 = {0.f, 0.f, 0.f, 0.f};
#pragma unroll
  for (int i = 0; i < 2; ++i)
#pragma unroll
    for (int j = 0; j < 4; ++j) acc[i][j] = z4;

  stage(0, 0);
  __syncthreads();
  int cur = 0;
  for (int kt = 0; kt < DM / 32; ++kt) {
    if (kt + 1 < DM / 32) stage(cur ^ 1, kt + 1);
    bf16x8 aF[2], bF[4];
#pragma unroll
    for (int mi = 0; mi < 2; ++mi)
      aF[mi] = *(const bf16x8*)(&sA[cur][(wr * 32 + mi * 16 + li) * 32 + lg * 8]);
#pragma unroll
    for (int ni = 0; ni < 4; ++ni)
      bF[ni] = *(const bf16x8*)(&sB[cur][(wc * 64 + ni * 16 + li) * 32 + lg * 8]);
#pragma unroll
    for (int mi = 0; mi < 2; ++mi)
#pragma unroll
      for (int ni = 0; ni < 4; ++ni)
        acc[mi][ni] = __builtin_amdgcn_mfma_f32_16x16x32_bf16(aF[mi], bF[ni], acc[mi][ni], 0, 0, 0);
    __syncthreads();
    cur ^= 1;
  }

  // epilogue: scatter Q (scaled log2e/8) / K / V^T with bias
#pragma unroll
  for (int mi = 0; mi < 2; ++mi) {
    const int m = m0 + wr * 32 + mi * 16 + lg * 4;
    const int b = m >> 11;
    const int s = m & 2047;
#pragma unroll
    for (int ni = 0; ni < 4; ++ni) {
      const int n = n0 + wc * 64 + ni * 16 + li;
      const int nn = n - (mode << 10);
      const int h = nn >> 6, dd = nn & 63;
      const float bia = bias[nn];
      const size_t bh = (size_t)(b * NH + h);
      if (mode == 2) {
        union { u16 h4[4]; uint2 u; } pk;
#pragma unroll
        for (int r = 0; r < 4; ++r) pk.h4[r] = f2b(acc[mi][ni][r] + bia);
        *(uint2*)(Vt + (bh * HD + dd) * SQ + s) = pk.u;
      } else {
#pragma unroll
        for (int r = 0; r < 4; ++r) {
          const float val = acc[mi][ni][r] + bia;
          const int ss = s + r;
          if (mode == 0) Qb[(bh * SQ + ss) * HD + dd] = f2b(val * 0.180336880f);
          else           Kb[(bh * SQ + ss) * HD + dd] = f2b(val);
        }
      }
    }
  }
}

// ---------------------------------------------------------------------------
// Final projection: out = Ao * Wo^T + bo (bf16 in, fp32 out). R9 version.
// ---------------------------------------------------------------------------
__global__ void __launch_bounds__(256) out_gemm(
    const u16* __restrict__ Ag, const u16* __restrict__ Wob,
    const float* __restrict__ bo, float* __restrict__ out) {
  __shared__ u16 sA[2][2048];
  __shared__ u16 sB[2][4096];
  const int t = threadIdx.x, l = t & 63, w = t >> 6;
  const int wr = w >> 1, wc = w & 1, lg = l >> 4, li = l & 15;
  const int m0 = blockIdx.y * 64, n0 = blockIdx.x * 128;

  auto stage = [&](int buf, int kt) {
    {
      const int s = w * 64 + l;
      const int r = s >> 2, cc = s & 3;
      gll16(Ag + (size_t)(m0 + r) * DM + kt * 32 + cc * 8, &sA[buf][w * 512]);
    }
#pragma unroll
    for (int c = 0; c < 2; ++c) {
      const int g = w * 2 + c;
      const int s = g * 64 + l;
      const int r = s >> 2, cc = s & 3;
      gll16(Wob + (size_t)(n0 + r) * DM + kt * 32 + cc * 8, &sB[buf][g * 512]);
    }
  };

  f32x4 acc[2][4];
  f32x4 z4 = {0.f, 0.f, 0.f, 0.f};
#pragma unroll
  for (int i = 0; i < 2; ++i)
#pragma unroll
    for (int j = 0; j < 4; ++j) acc[i][j] = z4;

  stage(0, 0);
  __syncthreads();
  int cur = 0;
  for (int kt = 0; kt < DM / 32; ++kt) {
    if (kt + 1 < DM / 32) stage(cur ^ 1, kt + 1);
    bf16x8 aF[2], bF[4];
#pragma unroll
    for (int mi = 0; mi < 2; ++mi)
      aF[mi] = *(const bf16x8*)(&sA[cur][(wr * 32 + mi * 16 + li) * 32 + lg * 8]);
#pragma unroll
    for (int ni = 0; ni < 4; ++ni)
      bF[ni] = *(const bf16x8*)(&sB[cur][(wc * 64 + ni * 16 + li) * 32 + lg * 8]);
#pragma unroll
    for (int mi = 0; mi < 2; ++mi)
#pragma unroll
      for (int ni = 0; ni < 4; ++ni)
        acc[mi][ni] = __builtin_amdgcn_mfma_f32_16x16x32_bf16(aF[mi], bF[ni], acc[mi][ni], 0, 0, 0);
    __syncthreads();
    cur ^= 1;
  }

#pragma unroll
  for (int mi = 0; mi < 2; ++mi) {
    const int m = m0 + wr * 32 + mi * 16 + lg * 4;
#pragma unroll
    for (int ni = 0; ni < 4; ++ni) {
      const int n = n0 + wc * 64 + ni * 16 + li;
      const float bia = bo[n];
#pragma unroll
      for (int r = 0; r < 4; ++r)
        out[(size_t)(m + r) * DM + n] = acc[mi][ni][r] + bia;
    }
  }
}

// ---------------------------------------------------------------------------
// Flash attention v15 (measured best), grid 512.
// ---------------------------------------------------------------------------
__global__ void __launch_bounds__(256, 2) attn_v15(
    const u16* __restrict__ Qb, const u16* __restrict__ Kb, const u16* __restrict__ Vt,
    const int* __restrict__ vlen, const int* __restrict__ wl, u16* __restrict__ Ao) {
  __shared__ u16 sKV[4][10240];
  const int t = threadIdx.x, w = t >> 6, l = t & 63, lg = l >> 4, li = l & 15;
  const int nit = wl[0];

  int kOff[4], vOff[4];
#pragma unroll
  for (int i = 0; i < 4; ++i) {
    {
      const int s = i * 64 + l, row = s >> 3, c = s & 7;
      const int csrc = c ^ (row & 7);
      const int sig = (((row >> 2) & 3) << 3) | (((row >> 4) & 1) << 2) | (row & 3);
      kOff[i] = sig * HD + csrc * 8;
    }
    {
      const int s = i * 64 + l, d = s >> 2, c = s & 3;
      const int csrc = c ^ ((d >> 2) & 3);
      vOff[i] = d * SQ + csrc * 8;
    }
  }

  u16* sw = &sKV[w][0];
  f32x4* op = (f32x4*)&sKV[0][0];
  float* lp = (float*)((char*)&sKV[0][0] + 65536);

  for (int it = blockIdx.x; it < nit; it += gridDim.x) {
    const int item = wl[1 + it];
    const int bh = item >> 5, qt = item & 31;
    const int vl = vlen[bh];
    const int q0 = qt * 64;
    const int b = bh >> 4, h = bh & 15;
    const u16* Qh = Qb + (size_t)bh * SQ * HD;
    const u16* Kh = Kb + (size_t)bh * SQ * HD;
    const u16* Vh = Vt + (size_t)bh * HD * SQ;
    const int k0 = w * 512;

    bf16x8 qf[4][2];
#pragma unroll
    for (int g = 0; g < 4; ++g) {
      const bool mq = (q0 + g * 16 + li) >= vl;
#pragma unroll
      for (int kk = 0; kk < 2; ++kk) {
        qf[g][kk] = *(const bf16x8*)(Qh + (size_t)(q0 + g * 16 + li) * HD + kk * 32 + lg * 8);
        if (mq) {
          union { u32 u[4]; bf16x8 v; } z; z.u[0] = z.u[1] = z.u[2] = z.u[3] = 0;
          qf[g][kk] = z.v;
        }
      }
    }

    auto stageK = [&](int buf, int tt) {
      const u16* kb = Kh + (size_t)(k0 + tt * 32) * HD;
#pragma unroll
      for (int i = 0; i < 4; ++i) gll16(kb + kOff[i], sw + buf * 2048 + i * 512);
    };
    auto stageV = [&](int buf, int tt) {
      const u16* vb = Vh + (size_t)(k0 + tt * 32);
#pragma unroll
      for (int i = 0; i < 4; ++i) gll16(vb + vOff[i], sw + 6144 + buf * 2048 + i * 512);
    };

    f32x4 z4 = {0.f, 0.f, 0.f, 0.f};
    f32x4 acc[4][4];
    float lr[4] = {0.f, 0.f, 0.f, 0.f};
#pragma unroll
    for (int g = 0; g < 4; ++g)
#pragma unroll
      for (int n2 = 0; n2 < 4; ++n2) acc[g][n2] = z4;

    stageV(0, 0); stageK(0, 0); stageK(1, 1);
    for (int tt = 0; tt < 16; ++tt) {
      if (tt + 1 < 16) stageV((tt + 1) & 1, tt + 1);
      if (tt + 2 < 16) stageK((tt + 2) % 3, tt + 2);
      if (tt <= 13)      asm volatile("s_waitcnt vmcnt(12)" ::: "memory");
      else if (tt == 14) asm volatile("s_waitcnt vmcnt(8)" ::: "memory");
      else               asm volatile("s_waitcnt vmcnt(0)" ::: "memory");
      const u16* kb_ = sw + (tt % 3) * 2048;
      const u16* vb_ = sw + 6144 + (tt & 1) * 2048;

      bf16x8 kf[2][2], vf[4];
#pragma unroll
      for (int ni = 0; ni < 2; ++ni) {
        const int row = ni * 16 + li;
        kf[ni][0] = *(const bf16x8*)(kb_ + row * 64 + ((lg ^ (row & 7)) * 8));
        kf[ni][1] = *(const bf16x8*)(kb_ + row * 64 + (((4 + lg) ^ (row & 7)) * 8));
      }
#pragma unroll
      for (int n2 = 0; n2 < 4; ++n2) {
        const int d = n2 * 16 + li;
        vf[n2] = *(const bf16x8*)(vb_ + d * 32 + ((lg ^ ((d >> 2) & 3)) * 8));
      }

      f32x4 s0a[4], s1a[4];
      __builtin_amdgcn_s_setprio(1);
#pragma unroll
      for (int g = 0; g < 4; ++g) {
        s0a[g] = __builtin_amdgcn_mfma_f32_16x16x32_bf16(kf[0][0], qf[g][0], z4, 0, 0, 0);
        s1a[g] = __builtin_amdgcn_mfma_f32_16x16x32_bf16(kf[1][0], qf[g][0], z4, 0, 0, 0);
      }
#pragma unroll
      for (int g = 0; g < 4; ++g) {
        s0a[g] = __builtin_amdgcn_mfma_f32_16x16x32_bf16(kf[0][1], qf[g][1], s0a[g], 0, 0, 0);
        s1a[g] = __builtin_amdgcn_mfma_f32_16x16x32_bf16(kf[1][1], qf[g][1], s1a[g], 0, 0, 0);
      }
      __builtin_amdgcn_s_setprio(0);

      bf16x8 Pv[4];
#pragma unroll
      for (int g = 0; g < 4; ++g) {
        union { __bf16 e[8]; bf16x8 v; } P;
        float ls = 0.f;
#pragma unroll
        for (int r = 0; r < 4; ++r) {
          const float p0 = __builtin_amdgcn_exp2f(s0a[g][r]);
          const float p1 = __builtin_amdgcn_exp2f(s1a[g][r]);
          P.e[r]     = (__bf16)p0;
          P.e[4 + r] = (__bf16)p1;
          ls += p0 + p1;
        }
        lr[g] += ls;
        Pv[g] = P.v;
      }

      __builtin_amdgcn_s_setprio(1);
#pragma unroll
      for (int g = 0; g < 4; ++g)
#pragma unroll
        for (int n2 = 0; n2 < 4; ++n2)
          acc[g][n2] = __builtin_amdgcn_mfma_f32_16x16x32_bf16(vf[n2], Pv[g], acc[g][n2], 0, 0, 0);
      __builtin_amdgcn_s_setprio(0);
    }

    __syncthreads();
#pragma unroll
    for (int g = 0; g < 4; ++g) {
#pragma unroll
      for (int n2 = 0; n2 < 4; ++n2)
        op[(((w * 4) + g) * 4 + n2) * 64 + l] = acc[g][n2];
      float v = lr[g];
      v += __shfl_xor(v, 16);
      v += __shfl_xor(v, 32);
      if (lg == 0) lp[(w * 4 + g) * 16 + li] = v;
    }
    __syncthreads();

    const int g = w;
    const float lf = lp[(0 * 4 + g) * 16 + li] + lp[(1 * 4 + g) * 16 + li]
                   + lp[(2 * 4 + g) * 16 + li] + lp[(3 * 4 + g) * 16 + li];
    const float inv = 1.0f / lf;
    const size_t rowb = ((size_t)(b * SQ + q0 + g * 16 + li)) * DM + h * HD;
#pragma unroll
    for (int n2 = 0; n2 < 4; ++n2) {
      f32x4 s = op[((0 * 4 + g) * 4 + n2) * 64 + l];
      s += op[((1 * 4 + g) * 4 + n2) * 64 + l];
      s += op[((2 * 4 + g) * 4 + n2) * 64 + l];
      s += op[((3 * 4 + g) * 4 + n2) * 64 + l];
      union { __bf16 h2[4]; uint2 u; } ov;
#pragma unroll
      for (int r = 0; r < 4; ++r) ov.h2[r] = (__bf16)(s[r] * inv);
      *(uint2*)(Ao + rowb + n2 * 16 + lg * 4) = ov.u;
    }
    __syncthreads();
  }
}

extern "C" void kernel_launch(void* const* d_in, const int* in_sizes, int n_in,
                              void* d_out, int out_size, void* d_ws, size_t ws_size,
                              hipStream_t stream) {
  const float* X  = (const float*)d_in[0];
  const float* Wq = (const float*)d_in[1];
  const float* bq = (const float*)d_in[2];
  const float* Wk = (const float*)d_in[3];
  const float* bk = (const float*)d_in[4];
  const float* Wv = (const float*)d_in[5];
  const float* bv = (const float*)d_in[6];
  const float* Wo = (const float*)d_in[7];
  const float* bo = (const float*)d_in[8];
  const int* vlen = (const int*)d_in[9];

  char* ws = (char*)d_ws;
  u16* Qb  = (u16*)(ws);                       // 8 MB [32][2048][64]
  u16* Kb  = (u16*)(ws + (size_t)8388608);     // 8 MB
  u16* Vt  = (u16*)(ws + (size_t)16777216);    // 8 MB [32][64][2048]
  u16* Xb  = (u16*)(ws + (size_t)25165824);    // 8 MB [4096][1024] bf16
  u16* Ao  = Xb;                               // alias: Xb dead after qkv
  u16* Wqb = (u16*)(ws + (size_t)33554432);    // 2 MB each; Wq/Wk/Wv contiguous
  u16* Wkb = (u16*)(ws + (size_t)35651584);
  u16* Wvb = (u16*)(ws + (size_t)37748736);
  u16* Wob = (u16*)(ws + (size_t)39845888);    // ends at 40 MB

  int* wl = (int*)((char*)d_out + 8192);

  dim3 blk(256);
  conv_bf16<<<4096, blk, 0, stream>>>(X, Wq, Wk, Wv, Wo, Xb, Wqb, Wkb, Wvb, Wob);
  qkv_gemm64<<<1536, blk, 0, stream>>>(Xb, Wqb, bq, bk, bv, vlen, Qb, Kb, Vt);
  mean_v2<<<dim3(32, 8), blk, 0, stream>>>(Vt, vlen, Ao, wl);
  attn_v15<<<512, blk, 0, stream>>>(Qb, Kb, Vt, vlen, wl, Ao);
  out_gemm<<<dim3(8, 64), blk, 0, stream>>>(Ao, Wob, bo, (float*)d_out);
}

// Round 25
// 116.526 us; speedup vs baseline: 1.2032x; 1.2032x over previous
//
#include <hip/hip_runtime.h>

#define SQ 2048
#define DM 1024
#define NH 16
#define HD 64

typedef __bf16 bf16x8 __attribute__((ext_vector_type(8)));
typedef float f32x4 __attribute__((ext_vector_type(4)));
typedef unsigned short u16;
typedef unsigned int u32;

// fp32 -> bf16 round-to-nearest-even (bulk convert pass)
__device__ __forceinline__ u16 f2b(float f) {
  union { float f; u32 u; } c; c.f = f;
  return (u16)((c.u + 0x7FFFu + ((c.u >> 16) & 1u)) >> 16);
}

// async global->LDS, 16B per lane; lds dest = wave-uniform base + lane*16
__device__ __forceinline__ void gll16(const void* g, void* l) {
  __builtin_amdgcn_global_load_lds(
      (const __attribute__((address_space(1))) void*)g,
      (__attribute__((address_space(3))) void*)l, 16, 0, 0);
}

// ---------------------------------------------------------------------------
// fp32 -> bf16 convert pass: X (4M elems) + Wq/Wk/Wv/Wo (1M each)
// ---------------------------------------------------------------------------
__global__ void __launch_bounds__(256) conv_bf16(
    const float* __restrict__ X,
    const float* __restrict__ Wq, const float* __restrict__ Wk,
    const float* __restrict__ Wv, const float* __restrict__ Wo,
    u16* __restrict__ Xb, u16* __restrict__ Wqb, u16* __restrict__ Wkb,
    u16* __restrict__ Wvb, u16* __restrict__ Wob) {
  const size_t e = ((size_t)blockIdx.x * 256 + threadIdx.x) * 8;
  const float* src; u16* dst; size_t rel;
  if (e < 4194304u)      { src = X;  dst = Xb;  rel = e; }
  else if (e < 5242880u) { src = Wq; dst = Wqb; rel = e - 4194304u; }
  else if (e < 6291456u) { src = Wk; dst = Wkb; rel = e - 5242880u; }
  else if (e < 7340032u) { src = Wv; dst = Wvb; rel = e - 6291456u; }
  else                   { src = Wo; dst = Wob; rel = e - 7340032u; }
  float4 a = *(const float4*)(src + rel);
  float4 b = *(const float4*)(src + rel + 4);
  union { u16 h[8]; uint4 v; } o;
  o.h[0] = f2b(a.x); o.h[1] = f2b(a.y); o.h[2] = f2b(a.z); o.h[3] = f2b(a.w);
  o.h[4] = f2b(b.x); o.h[5] = f2b(b.y); o.h[6] = f2b(b.z); o.h[7] = f2b(b.w);
  *(uint4*)(dst + rel) = o.v;
}

// ---------------------------------------------------------------------------
// mean_v2: per (bh, stripe): compute mean(V), fill masked q-rows of Ao;
// block (0,0) builds the active-tile work list.
// ---------------------------------------------------------------------------
__global__ void __launch_bounds__(256) mean_v2(
    const u16* __restrict__ Vt, const int* __restrict__ vlen,
    u16* __restrict__ Ao, int* __restrict__ wl) {
  __shared__ float part[256];
  __shared__ float smv[64];
  const int bh = blockIdx.x, c8 = blockIdx.y;
  const int t = threadIdx.x, d = t >> 2, c = t & 3;
  const u16* row = Vt + ((size_t)bh * HD + d) * SQ + c * 512;
  float s = 0.f;
  for (int i = 0; i < 64; ++i) {
    bf16x8 v = *(const bf16x8*)(row + i * 8);
    s += ((float)v[0] + (float)v[1]) + ((float)v[2] + (float)v[3])
       + ((float)v[4] + (float)v[5]) + ((float)v[6] + (float)v[7]);
  }
  part[t] = s;
  __syncthreads();
  if (c == 0) {
    const float tot = (part[t] + part[t + 1]) + (part[t + 2] + part[t + 3]);
    smv[d] = tot * (1.0f / 2048.0f);
  }
  __syncthreads();

  const int vl = vlen[bh];
  const int ft = (vl + 63) >> 6;
  const int b = bh >> 4, h = bh & 15;
  const int c16 = t & 15, r16 = t >> 4;
  union { u16 h4[4]; uint2 u; } pv;
#pragma unroll
  for (int j = 0; j < 4; ++j) pv.h4[j] = f2b(smv[c16 * 4 + j]);
  for (int ss = ft * 64 + c8 * 16 + r16; ss < SQ; ss += 128)
    *(uint2*)(Ao + ((size_t)(b * SQ + ss)) * DM + h * HD + c16 * 4) = pv.u;

  if (bh == 0 && c8 == 0) {
    __shared__ int nts[32], off[32];
    if (t < 32) {
      int nt = (vlen[t] + 63) >> 6;
      if (nt > 32) nt = 32;
      nts[t] = nt;
    }
    __syncthreads();
    if (t == 0) {
      int acc = 0;
      for (int i = 0; i < 32; ++i) { off[i] = acc; acc += nts[i]; }
      wl[0] = acc;
    }
    __syncthreads();
    if (t < 32) {
      const int o = off[t], nt = nts[t];
      for (int q = 0; q < nt; ++q) wl[1 + o + q] = (t << 5) | q;
    }
  }
}

// ---------------------------------------------------------------------------
// Merged QKV projection, 128x128 tile, 3-buffer LDS ring (48KB -> 3 blk/CU),
// single barrier per K-step, counted vmcnt, XOR swizzle. Grid 768. (R20 best)
// ---------------------------------------------------------------------------
__global__ void __launch_bounds__(256, 3) qkv_gemm(
    const u16* __restrict__ Xb, const u16* __restrict__ Wqkv,
    const float* __restrict__ bq, const float* __restrict__ bk, const float* __restrict__ bv,
    const int* __restrict__ vlen,
    u16* __restrict__ Qb, u16* __restrict__ Kb, u16* __restrict__ Vt) {
  __shared__ u16 sA[3][4096];
  __shared__ u16 sB[3][4096];
  const int id = blockIdx.x;
  const int swz = (id & 7) * 96 + (id >> 3);   // bijective: nwg=768
  const int bx = swz % 24, by = swz / 24;
  const int m0 = by * 128, n0 = bx * 128;
  const int mode = n0 >> 10;
  const float* bias = (mode == 0) ? bq : (mode == 1) ? bk : bv;

  if (mode == 0) {
    const int bb = m0 >> 11, s0 = m0 & 2047, h0 = n0 >> 6;
    if (s0 >= vlen[bb * NH + h0] && s0 >= vlen[bb * NH + h0 + 1]) return;
  }

  const int t = threadIdx.x, l = t & 63, w = t >> 6;
  const int wr = w >> 1, wc = w & 1, lg = l >> 4, li = l & 15;

  int srcOff[2];
#pragma unroll
  for (int j = 0; j < 2; ++j) {
    const int g = w * 2 + j;
    const int row = g * 16 + (l >> 2);
    const int colsrc = ((l & 3) * 8) ^ (((row >> 3) & 1) << 4);
    srcOff[j] = row * DM + colsrc;
  }
  const u16* Abase = Xb + (size_t)m0 * DM;
  const u16* Bbase = Wqkv + (size_t)n0 * DM;

  auto stage = [&](int buf, int kt) {
#pragma unroll
    for (int j = 0; j < 2; ++j) {
      gll16(Abase + srcOff[j] + kt * 32, &sA[buf][(w * 2 + j) * 512]);
      gll16(Bbase + srcOff[j] + kt * 32, &sB[buf][(w * 2 + j) * 512]);
    }
  };

  f32x4 acc[4][4];
  f32x4 z4 = {0.f, 0.f, 0.f, 0.f};
#pragma unroll
  for (int i = 0; i < 4; ++i)
#pragma unroll
    for (int j = 0; j < 4; ++j) acc[i][j] = z4;

  stage(0, 0);
  stage(1, 1);
  for (int kt = 0; kt < 32; ++kt) {
    const int bsel = kt % 3;
    if (kt < 31) asm volatile("s_waitcnt vmcnt(4)" ::: "memory");
    else         asm volatile("s_waitcnt vmcnt(0)" ::: "memory");
    __builtin_amdgcn_s_barrier();            // publishes buf kt to all waves
    asm volatile("" ::: "memory");

    bf16x8 aF[4], bF[4];
#pragma unroll
    for (int mi = 0; mi < 4; ++mi) {
      const int rl = wr * 64 + mi * 16 + li;
      aF[mi] = *(const bf16x8*)(&sA[bsel][rl * 32 + ((lg * 8) ^ (((rl >> 3) & 1) << 4))]);
    }
#pragma unroll
    for (int ni = 0; ni < 4; ++ni) {
      const int rn = wc * 64 + ni * 16 + li;
      bF[ni] = *(const bf16x8*)(&sB[bsel][rn * 32 + ((lg * 8) ^ (((rn >> 3) & 1) << 4))]);
    }
    if (kt + 2 < 32) stage((kt + 2) % 3, kt + 2);

    __builtin_amdgcn_s_setprio(1);
#pragma unroll
    for (int mi = 0; mi < 4; ++mi)
#pragma unroll
      for (int ni = 0; ni < 4; ++ni)
        acc[mi][ni] = __builtin_amdgcn_mfma_f32_16x16x32_bf16(aF[mi], bF[ni], acc[mi][ni], 0, 0, 0);
    __builtin_amdgcn_s_setprio(0);
  }

#pragma unroll
  for (int mi = 0; mi < 4; ++mi) {
    const int m = m0 + wr * 64 + mi * 16 + lg * 4;
    const int b = m >> 11;
    const int s = m & 2047;
#pragma unroll
    for (int ni = 0; ni < 4; ++ni) {
      const int n = n0 + wc * 64 + ni * 16 + li;
      const int nn = n - (mode << 10);
      const int h = nn >> 6, dd = nn & 63;
      const float bia = bias[nn];
      const size_t bh = (size_t)(b * NH + h);
      if (mode == 2) {
        union { u16 h4[4]; uint2 u; } pk;
#pragma unroll
        for (int r = 0; r < 4; ++r) pk.h4[r] = f2b(acc[mi][ni][r] + bia);
        *(uint2*)(Vt + (bh * HD + dd) * SQ + s) = pk.u;
      } else {
#pragma unroll
        for (int r = 0; r < 4; ++r) {
          const float val = acc[mi][ni][r] + bia;
          const int ss = s + r;
          if (mode == 0) Qb[(bh * SQ + ss) * HD + dd] = f2b(val * 0.180336880f);
          else           Kb[(bh * SQ + ss) * HD + dd] = f2b(val);
        }
      }
    }
  }
}

// ---------------------------------------------------------------------------
// Final projection: out = Ao * Wo^T + bo (bf16 in, fp32 out). R9 version.
// ---------------------------------------------------------------------------
__global__ void __launch_bounds__(256) out_gemm(
    const u16* __restrict__ Ag, const u16* __restrict__ Wob,
    const float* __restrict__ bo, float* __restrict__ out) {
  __shared__ u16 sA[2][2048];
  __shared__ u16 sB[2][4096];
  const int t = threadIdx.x, l = t & 63, w = t >> 6;
  const int wr = w >> 1, wc = w & 1, lg = l >> 4, li = l & 15;
  const int m0 = blockIdx.y * 64, n0 = blockIdx.x * 128;

  auto stage = [&](int buf, int kt) {
    {
      const int s = w * 64 + l;
      const int r = s >> 2, cc = s & 3;
      gll16(Ag + (size_t)(m0 + r) * DM + kt * 32 + cc * 8, &sA[buf][w * 512]);
    }
#pragma unroll
    for (int c = 0; c < 2; ++c) {
      const int g = w * 2 + c;
      const int s = g * 64 + l;
      const int r = s >> 2, cc = s & 3;
      gll16(Wob + (size_t)(n0 + r) * DM + kt * 32 + cc * 8, &sB[buf][g * 512]);
    }
  };

  f32x4 acc[2][4];
  f32x4 z4 = {0.f, 0.f, 0.f, 0.f};
#pragma unroll
  for (int i = 0; i < 2; ++i)
#pragma unroll
    for (int j = 0; j < 4; ++j) acc[i][j] = z4;

  stage(0, 0);
  __syncthreads();
  int cur = 0;
  for (int kt = 0; kt < DM / 32; ++kt) {
    if (kt + 1 < DM / 32) stage(cur ^ 1, kt + 1);
    bf16x8 aF[2], bF[4];
#pragma unroll
    for (int mi = 0; mi < 2; ++mi)
      aF[mi] = *(const bf16x8*)(&sA[cur][(wr * 32 + mi * 16 + li) * 32 + lg * 8]);
#pragma unroll
    for (int ni = 0; ni < 4; ++ni)
      bF[ni] = *(const bf16x8*)(&sB[cur][(wc * 64 + ni * 16 + li) * 32 + lg * 8]);
#pragma unroll
    for (int mi = 0; mi < 2; ++mi)
#pragma unroll
      for (int ni = 0; ni < 4; ++ni)
        acc[mi][ni] = __builtin_amdgcn_mfma_f32_16x16x32_bf16(aF[mi], bF[ni], acc[mi][ni], 0, 0, 0);
    __syncthreads();
    cur ^= 1;
  }

#pragma unroll
  for (int mi = 0; mi < 2; ++mi) {
    const int m = m0 + wr * 32 + mi * 16 + lg * 4;
#pragma unroll
    for (int ni = 0; ni < 4; ++ni) {
      const int n = n0 + wc * 64 + ni * 16 + li;
      const float bia = bo[n];
#pragma unroll
      for (int r = 0; r < 4; ++r)
        out[(size_t)(m + r) * DM + n] = acc[mi][ni][r] + bia;
    }
  }
}

// ---------------------------------------------------------------------------
// Flash attention v15 (measured best), grid 512.
// ---------------------------------------------------------------------------
__global__ void __launch_bounds__(256, 2) attn_v15(
    const u16* __restrict__ Qb, const u16* __restrict__ Kb, const u16* __restrict__ Vt,
    const int* __restrict__ vlen, const int* __restrict__ wl, u16* __restrict__ Ao) {
  __shared__ u16 sKV[4][10240];
  const int t = threadIdx.x, w = t >> 6, l = t & 63, lg = l >> 4, li = l & 15;
  const int nit = wl[0];

  int kOff[4], vOff[4];
#pragma unroll
  for (int i = 0; i < 4; ++i) {
    {
      const int s = i * 64 + l, row = s >> 3, c = s & 7;
      const int csrc = c ^ (row & 7);
      const int sig = (((row >> 2) & 3) << 3) | (((row >> 4) & 1) << 2) | (row & 3);
      kOff[i] = sig * HD + csrc * 8;
    }
    {
      const int s = i * 64 + l, d = s >> 2, c = s & 3;
      const int csrc = c ^ ((d >> 2) & 3);
      vOff[i] = d * SQ + csrc * 8;
    }
  }

  u16* sw = &sKV[w][0];
  f32x4* op = (f32x4*)&sKV[0][0];
  float* lp = (float*)((char*)&sKV[0][0] + 65536);

  for (int it = blockIdx.x; it < nit; it += gridDim.x) {
    const int item = wl[1 + it];
    const int bh = item >> 5, qt = item & 31;
    const int vl = vlen[bh];
    const int q0 = qt * 64;
    const int b = bh >> 4, h = bh & 15;
    const u16* Qh = Qb + (size_t)bh * SQ * HD;
    const u16* Kh = Kb + (size_t)bh * SQ * HD;
    const u16* Vh = Vt + (size_t)bh * HD * SQ;
    const int k0 = w * 512;

    bf16x8 qf[4][2];
#pragma unroll
    for (int g = 0; g < 4; ++g) {
      const bool mq = (q0 + g * 16 + li) >= vl;
#pragma unroll
      for (int kk = 0; kk < 2; ++kk) {
        qf[g][kk] = *(const bf16x8*)(Qh + (size_t)(q0 + g * 16 + li) * HD + kk * 32 + lg * 8);
        if (mq) {
          union { u32 u[4]; bf16x8 v; } z; z.u[0] = z.u[1] = z.u[2] = z.u[3] = 0;
          qf[g][kk] = z.v;
        }
      }
    }

    auto stageK = [&](int buf, int tt) {
      const u16* kb = Kh + (size_t)(k0 + tt * 32) * HD;
#pragma unroll
      for (int i = 0; i < 4; ++i) gll16(kb + kOff[i], sw + buf * 2048 + i * 512);
    };
    auto stageV = [&](int buf, int tt) {
      const u16* vb = Vh + (size_t)(k0 + tt * 32);
#pragma unroll
      for (int i = 0; i < 4; ++i) gll16(vb + vOff[i], sw + 6144 + buf * 2048 + i * 512);
    };

    f32x4 z4 = {0.f, 0.f, 0.f, 0.f};
    f32x4 acc[4][4];
    float lr[4] = {0.f, 0.f, 0.f, 0.f};
#pragma unroll
    for (int g = 0; g < 4; ++g)
#pragma unroll
      for (int n2 = 0; n2 < 4; ++n2) acc[g][n2] = z4;

    stageV(0, 0); stageK(0, 0); stageK(1, 1);
    for (int tt = 0; tt < 16; ++tt) {
      if (tt + 1 < 16) stageV((tt + 1) & 1, tt + 1);
      if (tt + 2 < 16) stageK((tt + 2) % 3, tt + 2);
      if (tt <= 13)      asm volatile("s_waitcnt vmcnt(12)" ::: "memory");
      else if (tt == 14) asm volatile("s_waitcnt vmcnt(8)" ::: "memory");
      else               asm volatile("s_waitcnt vmcnt(0)" ::: "memory");
      const u16* kb_ = sw + (tt % 3) * 2048;
      const u16* vb_ = sw + 6144 + (tt & 1) * 2048;

      bf16x8 kf[2][2], vf[4];
#pragma unroll
      for (int ni = 0; ni < 2; ++ni) {
        const int row = ni * 16 + li;
        kf[ni][0] = *(const bf16x8*)(kb_ + row * 64 + ((lg ^ (row & 7)) * 8));
        kf[ni][1] = *(const bf16x8*)(kb_ + row * 64 + (((4 + lg) ^ (row & 7)) * 8));
      }
#pragma unroll
      for (int n2 = 0; n2 < 4; ++n2) {
        const int d = n2 * 16 + li;
        vf[n2] = *(const bf16x8*)(vb_ + d * 32 + ((lg ^ ((d >> 2) & 3)) * 8));
      }

      f32x4 s0a[4], s1a[4];
      __builtin_amdgcn_s_setprio(1);
#pragma unroll
      for (int g = 0; g < 4; ++g) {
        s0a[g] = __builtin_amdgcn_mfma_f32_16x16x32_bf16(kf[0][0], qf[g][0], z4, 0, 0, 0);
        s1a[g] = __builtin_amdgcn_mfma_f32_16x16x32_bf16(kf[1][0], qf[g][0], z4, 0, 0, 0);
      }
#pragma unroll
      for (int g = 0; g < 4; ++g) {
        s0a[g] = __builtin_amdgcn_mfma_f32_16x16x32_bf16(kf[0][1], qf[g][1], s0a[g], 0, 0, 0);
        s1a[g] = __builtin_amdgcn_mfma_f32_16x16x32_bf16(kf[1][1], qf[g][1], s1a[g], 0, 0, 0);
      }
      __builtin_amdgcn_s_setprio(0);

      bf16x8 Pv[4];
#pragma unroll
      for (int g = 0; g < 4; ++g) {
        union { __bf16 e[8]; bf16x8 v; } P;
        float ls = 0.f;
#pragma unroll
        for (int r = 0; r < 4; ++r) {
          const float p0 = __builtin_amdgcn_exp2f(s0a[g][r]);
          const float p1 = __builtin_amdgcn_exp2f(s1a[g][r]);
          P.e[r]     = (__bf16)p0;
          P.e[4 + r] = (__bf16)p1;
          ls += p0 + p1;
        }
        lr[g] += ls;
        Pv[g] = P.v;
      }

      __builtin_amdgcn_s_setprio(1);
#pragma unroll
      for (int g = 0; g < 4; ++g)
#pragma unroll
        for (int n2 = 0; n2 < 4; ++n2)
          acc[g][n2] = __builtin_amdgcn_mfma_f32_16x16x32_bf16(vf[n2], Pv[g], acc[g][n2], 0, 0, 0);
      __builtin_amdgcn_s_setprio(0);
    }

    __syncthreads();
#pragma unroll
    for (int g = 0; g < 4; ++g) {
#pragma unroll
      for (int n2 = 0; n2 < 4; ++n2)
        op[(((w * 4) + g) * 4 + n2) * 64 + l] = acc[g][n2];
      float v = lr[g];
      v += __shfl_xor(v, 16);
      v += __shfl_xor(v, 32);
      if (lg == 0) lp[(w * 4 + g) * 16 + li] = v;
    }
    __syncthreads();

    const int g = w;
    const float lf = lp[(0 * 4 + g) * 16 + li] + lp[(1 * 4 + g) * 16 + li]
                   + lp[(2 * 4 + g) * 16 + li] + lp[(3 * 4 + g) * 16 + li];
    const float inv = 1.0f / lf;
    const size_t rowb = ((size_t)(b * SQ + q0 + g * 16 + li)) * DM + h * HD;
#pragma unroll
    for (int n2 = 0; n2 < 4; ++n2) {
      f32x4 s = op[((0 * 4 + g) * 4 + n2) * 64 + l];
      s += op[((1 * 4 + g) * 4 + n2) * 64 + l];
      s += op[((2 * 4 + g) * 4 + n2) * 64 + l];
      s += op[((3 * 4 + g) * 4 + n2) * 64 + l];
      union { __bf16 h2[4]; uint2 u; } ov;
#pragma unroll
      for (int r = 0; r < 4; ++r) ov.h2[r] = (__bf16)(s[r] * inv);
      *(uint2*)(Ao + rowb + n2 * 16 + lg * 4) = ov.u;
    }
    __syncthreads();
  }
}

extern "C" void kernel_launch(void* const* d_in, const int* in_sizes, int n_in,
                              void* d_out, int out_size, void* d_ws, size_t ws_size,
                              hipStream_t stream) {
  const float* X  = (const float*)d_in[0];
  const float* Wq = (const float*)d_in[1];
  const float* bq = (const float*)d_in[2];
  const float* Wk = (const float*)d_in[3];
  const float* bk = (const float*)d_in[4];
  const float* Wv = (const float*)d_in[5];
  const float* bv = (const float*)d_in[6];
  const float* Wo = (const float*)d_in[7];
  const float* bo = (const float*)d_in[8];
  const int* vlen = (const int*)d_in[9];

  char* ws = (char*)d_ws;
  u16* Qb  = (u16*)(ws);                       // 8 MB [32][2048][64]
  u16* Kb  = (u16*)(ws + (size_t)8388608);     // 8 MB
  u16* Vt  = (u16*)(ws + (size_t)16777216);    // 8 MB [32][64][2048]
  u16* Xb  = (u16*)(ws + (size_t)25165824);    // 8 MB [4096][1024] bf16
  u16* Ao  = Xb;                               // alias: Xb dead after qkv
  u16* Wqb = (u16*)(ws + (size_t)33554432);    // 2 MB each; Wq/Wk/Wv contiguous
  u16* Wkb = (u16*)(ws + (size_t)35651584);
  u16* Wvb = (u16*)(ws + (size_t)37748736);
  u16* Wob = (u16*)(ws + (size_t)39845888);    // ends at 40 MB

  int* wl = (int*)((char*)d_out + 8192);

  dim3 blk(256);
  conv_bf16<<<4096, blk, 0, stream>>>(X, Wq, Wk, Wv, Wo, Xb, Wqb, Wkb, Wvb, Wob);
  qkv_gemm<<<768, blk, 0, stream>>>(Xb, Wqb, bq, bk, bv, vlen, Qb, Kb, Vt);
  mean_v2<<<dim3(32, 8), blk, 0, stream>>>(Vt, vlen, Ao, wl);
  attn_v15<<<512, blk, 0, stream>>>(Qb, Kb, Vt, vlen, wl, Ao);
  out_gemm<<<dim3(8, 64), blk, 0, stream>>>(Ao, Wob, bo, (float*)d_out);
}